// Round 1
// baseline (299.849 us; speedup 1.0000x reference)
//
#include <hip/hip_runtime.h>
#include <hip/hip_bf16.h>

// Causal self-attention: qkv = x@w_qkv + b_qkv; flash-attn (causal); out = att@w_proj + b_proj
// B=4, T=2048, C=1024, H=16, D=64. All matmuls in bf16 MFMA (16x16x32), fp32 accumulate.

typedef __bf16 bf16x8 __attribute__((ext_vector_type(8)));
typedef float f32x4 __attribute__((ext_vector_type(4)));
typedef unsigned short u16x8 __attribute__((ext_vector_type(8)));
typedef unsigned short u16x4 __attribute__((ext_vector_type(4)));

#define LOG2E 1.44269504088896340736f

__device__ __forceinline__ unsigned short f2bf(float f) {
  unsigned int u = __builtin_bit_cast(unsigned int, f);
  u += 0x7fff + ((u >> 16) & 1);   // RNE
  return (unsigned short)(u >> 16);
}

__device__ __forceinline__ bf16x8 ld_frag(const unsigned short* p) {
  return __builtin_bit_cast(bf16x8, *reinterpret_cast<const u16x8*>(p));
}

// ---- fp32 -> bf16 elementwise (x) ----
__global__ void k_convert(const float* __restrict__ in, unsigned short* __restrict__ out, int n4) {
  int i = blockIdx.x * blockDim.x + threadIdx.x;
  int stride = gridDim.x * blockDim.x;
  for (; i < n4; i += stride) {
    float4 v = reinterpret_cast<const float4*>(in)[i];
    u16x4 o = { f2bf(v.x), f2bf(v.y), f2bf(v.z), f2bf(v.w) };
    reinterpret_cast<u16x4*>(out)[i] = o;
  }
}

// ---- fp32 [K][N] -> bf16 [N][K] transpose (weights) ----
__global__ void k_transpose(const float* __restrict__ in, unsigned short* __restrict__ out,
                            int K, int N) {
  __shared__ float tile[32][33];
  int n0 = blockIdx.x * 32, k0 = blockIdx.y * 32;
  int tx = threadIdx.x & 31, ty = threadIdx.x >> 5;  // 32 x 8
#pragma unroll
  for (int i = 0; i < 4; i++)
    tile[ty + i * 8][tx] = in[(size_t)(k0 + ty + i * 8) * N + n0 + tx];
  __syncthreads();
#pragma unroll
  for (int i = 0; i < 4; i++)
    out[(size_t)(n0 + ty + i * 8) * K + k0 + tx] = f2bf(tile[tx][ty + i * 8]);
}

// ---- bf16 GEMM: C[M][N] = A[M][K] @ Bt[N][K]^T + bias; OutT = bf16 or f32 ----
template <bool BF16_OUT>
__global__ __launch_bounds__(256) void k_gemm(
    const unsigned short* __restrict__ A, const unsigned short* __restrict__ Bt,
    const float* __restrict__ bias, void* __restrict__ Cv, int M, int N, int K) {
  constexpr int BK = 64, PAD = 8;
  __shared__ unsigned short Asm[128][BK + PAD];
  __shared__ unsigned short Bsm[128][BK + PAD];
  const int tid = threadIdx.x;
  const int lane = tid & 63, w = tid >> 6;
  const int wr = w >> 1, wc = w & 1;  // wave computes 64x64 at (wr,wc)
  const int brow = blockIdx.x * 128, bcol = blockIdx.y * 128;
  const int r0 = lane & 15, kq = lane >> 4;

  f32x4 acc[4][4] = {};

  const int srow = tid >> 3, sc8 = (tid & 7) * 8;  // staging: 8 threads/row

  for (int k0 = 0; k0 < K; k0 += BK) {
    __syncthreads();
#pragma unroll
    for (int p = 0; p < 4; p++) {
      int row = p * 32 + srow;
      *reinterpret_cast<u16x8*>(&Asm[row][sc8]) =
          *reinterpret_cast<const u16x8*>(&A[(size_t)(brow + row) * K + k0 + sc8]);
      *reinterpret_cast<u16x8*>(&Bsm[row][sc8]) =
          *reinterpret_cast<const u16x8*>(&Bt[(size_t)(bcol + row) * K + k0 + sc8]);
    }
    __syncthreads();
#pragma unroll
    for (int c = 0; c < 2; c++) {  // two K=32 chunks
      bf16x8 af[4], bfr[4];
#pragma unroll
      for (int m = 0; m < 4; m++)
        af[m] = ld_frag(&Asm[wr * 64 + m * 16 + r0][c * 32 + kq * 8]);
#pragma unroll
      for (int n = 0; n < 4; n++)
        bfr[n] = ld_frag(&Bsm[wc * 64 + n * 16 + r0][c * 32 + kq * 8]);
#pragma unroll
      for (int m = 0; m < 4; m++)
#pragma unroll
        for (int n = 0; n < 4; n++)
          acc[m][n] = __builtin_amdgcn_mfma_f32_16x16x32_bf16(af[m], bfr[n], acc[m][n], 0, 0, 0);
    }
  }

  const int orow = kq * 4;
#pragma unroll
  for (int n = 0; n < 4; n++) {
#pragma unroll
    for (int m = 0; m < 4; m++) {
      int col = bcol + wc * 64 + n * 16 + r0;
      float bv = bias[col];
#pragma unroll
      for (int r = 0; r < 4; r++) {
        int row = brow + wr * 64 + m * 16 + orow + r;
        float v = acc[m][n][r] + bv;
        if (BF16_OUT)
          ((unsigned short*)Cv)[(size_t)row * N + col] = f2bf(v);
        else
          ((float*)Cv)[(size_t)row * N + col] = v;
      }
    }
  }
}

// ---- causal flash attention ----
// qkv bf16 [B*T][3C]; att bf16 [B*T][C]. Block: one (b,h) x 64 q-rows; 4 waves x 16 rows.
__global__ __launch_bounds__(256) void k_flash(const unsigned short* __restrict__ qkv,
                                               unsigned short* __restrict__ att, int T) {
  constexpr int C3 = 3072, C = 1024, D = 64;
  __shared__ unsigned short Ksm[64][72];       // [tk][d]
  __shared__ unsigned short Vsm[64][72];       // transposed: [d][tk]
  __shared__ unsigned short Psm[4][16][72];    // per-wave P tile [q][tk]

  const int tid = threadIdx.x, lane = tid & 63, w = tid >> 6;
  const int bh = blockIdx.x;  // b*16 + h
  const int qt = blockIdx.y;
  const int b = bh >> 4, h = bh & 15;
  const int q0 = qt * 64;
  const int r0 = lane & 15, kq = lane >> 4;

  const size_t rowbase = (size_t)b * T * C3;

  // Q fragments (persist in registers)
  bf16x8 qf[2];
  {
    const unsigned short* qp = &qkv[rowbase + (size_t)(q0 + w * 16 + r0) * C3 + h * D];
#pragma unroll
    for (int c = 0; c < 2; c++) qf[c] = ld_frag(&qp[c * 32 + kq * 8]);
  }

  f32x4 accO[4] = {};
  float m_run[4], l_run[4];
#pragma unroll
  for (int r = 0; r < 4; r++) { m_run[r] = -__builtin_inff(); l_run[r] = 0.f; }

  const int qrow_my = q0 + w * 16 + kq * 4;  // this lane's acc rows base (global)

  const int stk = tid >> 3, sd8 = (tid & 7) * 8;  // staging map

  for (int kt = 0; kt <= qt; kt++) {
    const int k0 = kt * 64;
    __syncthreads();
    // stage K tile and V tile (V transposed into Vsm[d][tk])
#pragma unroll
    for (int p = 0; p < 2; p++) {
      int tkk = p * 32 + stk;
      const size_t rb = rowbase + (size_t)(k0 + tkk) * C3 + h * D + sd8;
      *reinterpret_cast<u16x8*>(&Ksm[tkk][sd8]) =
          *reinterpret_cast<const u16x8*>(&qkv[rb + C]);
      u16x8 vv = *reinterpret_cast<const u16x8*>(&qkv[rb + 2 * C]);
#pragma unroll
      for (int i = 0; i < 8; i++) Vsm[sd8 + i][tkk] = vv[i];
    }
    __syncthreads();

    // S = Q @ K^T (4 k-subtiles of 16)
    f32x4 sacc[4];
#pragma unroll
    for (int s = 0; s < 4; s++) {
      f32x4 a = {};
#pragma unroll
      for (int c = 0; c < 2; c++) {
        bf16x8 kf = ld_frag(&Ksm[s * 16 + r0][c * 32 + kq * 8]);
        a = __builtin_amdgcn_mfma_f32_16x16x32_bf16(qf[c], kf, a, 0, 0, 0);
      }
      sacc[s] = a;
    }

    // scale + causal mask
    float sv[4][4];
    const bool diag = (kt == qt);
#pragma unroll
    for (int s = 0; s < 4; s++) {
      int kcol = k0 + s * 16 + r0;
#pragma unroll
      for (int r = 0; r < 4; r++) {
        float x = sacc[s][r] * 0.125f;
        if (diag && kcol > qrow_my + r) x = -__builtin_inff();
        sv[s][r] = x;
      }
    }

    // row max (across 4 subtiles, then 16 lanes of the group)
    float corr[4];
#pragma unroll
    for (int r = 0; r < 4; r++) {
      float mx = fmaxf(fmaxf(sv[0][r], sv[1][r]), fmaxf(sv[2][r], sv[3][r]));
      mx = fmaxf(mx, __shfl_xor(mx, 1));
      mx = fmaxf(mx, __shfl_xor(mx, 2));
      mx = fmaxf(mx, __shfl_xor(mx, 4));
      mx = fmaxf(mx, __shfl_xor(mx, 8));
      float mn = fmaxf(m_run[r], mx);
      corr[r] = exp2f((m_run[r] - mn) * LOG2E);
      m_run[r] = mn;
    }

    // P = exp(S - m); write to wave-private LDS; accumulate row sums
    float ls[4] = {0.f, 0.f, 0.f, 0.f};
#pragma unroll
    for (int s = 0; s < 4; s++) {
#pragma unroll
      for (int r = 0; r < 4; r++) {
        float p = exp2f((sv[s][r] - m_run[r]) * LOG2E);
        ls[r] += p;
        Psm[w][kq * 4 + r][s * 16 + r0] = f2bf(p);
      }
    }
#pragma unroll
    for (int r = 0; r < 4; r++) {
      float t = ls[r];
      t += __shfl_xor(t, 1);
      t += __shfl_xor(t, 2);
      t += __shfl_xor(t, 4);
      t += __shfl_xor(t, 8);
      l_run[r] = l_run[r] * corr[r] + t;
    }
#pragma unroll
    for (int n = 0; n < 4; n++)
#pragma unroll
      for (int r = 0; r < 4; r++) accO[n][r] *= corr[r];

    // PV: A = P (from LDS round-trip), B = V (transposed in LDS)
    bf16x8 pf[2];
#pragma unroll
    for (int c = 0; c < 2; c++) pf[c] = ld_frag(&Psm[w][r0][c * 32 + kq * 8]);
#pragma unroll
    for (int n = 0; n < 4; n++) {
#pragma unroll
      for (int c = 0; c < 2; c++) {
        bf16x8 vf = ld_frag(&Vsm[n * 16 + r0][c * 32 + kq * 8]);
        accO[n] = __builtin_amdgcn_mfma_f32_16x16x32_bf16(pf[c], vf, accO[n], 0, 0, 0);
      }
    }
  }

  // epilogue: normalize, write att (bf16)
#pragma unroll
  for (int n = 0; n < 4; n++) {
#pragma unroll
    for (int r = 0; r < 4; r++) {
      int qrow = q0 + w * 16 + kq * 4 + r;
      float v = accO[n][r] / l_run[r];
      att[((size_t)b * T + qrow) * C + h * D + n * 16 + r0] = f2bf(v);
    }
  }
}

extern "C" void kernel_launch(void* const* d_in, const int* in_sizes, int n_in,
                              void* d_out, int out_size, void* d_ws, size_t ws_size,
                              hipStream_t stream) {
  const float* x = (const float*)d_in[0];
  const float* w_qkv = (const float*)d_in[1];
  const float* b_qkv = (const float*)d_in[2];
  const float* w_proj = (const float*)d_in[3];
  const float* b_proj = (const float*)d_in[4];

  constexpr int B = 4, T = 2048, C = 1024, C3 = 3072;
  constexpr int M = B * T;  // 8192

  unsigned short* x_bf = (unsigned short*)d_ws;            // M*C
  unsigned short* wqkvT = x_bf + (size_t)M * C;            // C3*C
  unsigned short* wprojT = wqkvT + (size_t)C3 * C;         // C*C
  unsigned short* qkv = wprojT + (size_t)C * C;            // M*C3
  unsigned short* att = qkv + (size_t)M * C3;              // M*C

  hipLaunchKernelGGL(k_convert, dim3(2048), dim3(256), 0, stream, x, x_bf, M * C / 4);
  hipLaunchKernelGGL(k_transpose, dim3(C3 / 32, C / 32), dim3(256), 0, stream, w_qkv, wqkvT, C, C3);
  hipLaunchKernelGGL(k_transpose, dim3(C / 32, C / 32), dim3(256), 0, stream, w_proj, wprojT, C, C);
  hipLaunchKernelGGL((k_gemm<true>), dim3(M / 128, C3 / 128), dim3(256), 0, stream,
                     x_bf, wqkvT, b_qkv, (void*)qkv, M, C3, C);
  hipLaunchKernelGGL(k_flash, dim3(64, 32), dim3(256), 0, stream, qkv, att, T);
  hipLaunchKernelGGL((k_gemm<false>), dim3(M / 128, C / 128), dim3(256), 0, stream,
                     att, wprojT, b_proj, d_out, M, C, C);
}

// Round 2
// 232.521 us; speedup vs baseline: 1.2896x; 1.2896x over previous
//
#include <hip/hip_runtime.h>
#include <hip/hip_bf16.h>

// Causal self-attention: qkv = x@w_qkv + b_qkv; flash-attn (causal); out = att@w_proj + b_proj
// B=4, T=2048, C=1024, H=16, D=64. All matmuls in bf16 MFMA (16x16x32), fp32 accumulate.
// R1: flash rewritten — swapped QK^T (S^T fragments => lane-local P rows), P kept in
// registers (no Psm), V^T stored with XOR swizzle (conflict-free scatter + b64 reads).

typedef __bf16 bf16x8 __attribute__((ext_vector_type(8)));
typedef float f32x4 __attribute__((ext_vector_type(4)));
typedef unsigned short u16x8 __attribute__((ext_vector_type(8)));
typedef unsigned short u16x4 __attribute__((ext_vector_type(4)));

#define LOG2E 1.44269504088896340736f
#define NEG_INF (-__builtin_inff())

__device__ __forceinline__ unsigned short f2bf(float f) {
  unsigned int u = __builtin_bit_cast(unsigned int, f);
  u += 0x7fff + ((u >> 16) & 1);   // RNE
  return (unsigned short)(u >> 16);
}

__device__ __forceinline__ bf16x8 ld_frag(const unsigned short* p) {
  return __builtin_bit_cast(bf16x8, *reinterpret_cast<const u16x8*>(p));
}

// ---- fp32 -> bf16 elementwise (x) ----
__global__ void k_convert(const float* __restrict__ in, unsigned short* __restrict__ out, int n4) {
  int i = blockIdx.x * blockDim.x + threadIdx.x;
  int stride = gridDim.x * blockDim.x;
  for (; i < n4; i += stride) {
    float4 v = reinterpret_cast<const float4*>(in)[i];
    u16x4 o = { f2bf(v.x), f2bf(v.y), f2bf(v.z), f2bf(v.w) };
    reinterpret_cast<u16x4*>(out)[i] = o;
  }
}

// ---- fp32 [K][N] -> bf16 [N][K] transpose (weights) ----
__global__ void k_transpose(const float* __restrict__ in, unsigned short* __restrict__ out,
                            int K, int N) {
  __shared__ float tile[32][33];
  int n0 = blockIdx.x * 32, k0 = blockIdx.y * 32;
  int tx = threadIdx.x & 31, ty = threadIdx.x >> 5;  // 32 x 8
#pragma unroll
  for (int i = 0; i < 4; i++)
    tile[ty + i * 8][tx] = in[(size_t)(k0 + ty + i * 8) * N + n0 + tx];
  __syncthreads();
#pragma unroll
  for (int i = 0; i < 4; i++)
    out[(size_t)(n0 + ty + i * 8) * K + k0 + tx] = f2bf(tile[tx][ty + i * 8]);
}

// ---- bf16 GEMM: C[M][N] = A[M][K] @ Bt[N][K]^T + bias; OutT = bf16 or f32 ----
template <bool BF16_OUT>
__global__ __launch_bounds__(256) void k_gemm(
    const unsigned short* __restrict__ A, const unsigned short* __restrict__ Bt,
    const float* __restrict__ bias, void* __restrict__ Cv, int M, int N, int K) {
  constexpr int BK = 64, PAD = 8;
  __shared__ unsigned short Asm[128][BK + PAD];
  __shared__ unsigned short Bsm[128][BK + PAD];
  const int tid = threadIdx.x;
  const int lane = tid & 63, w = tid >> 6;
  const int wr = w >> 1, wc = w & 1;  // wave computes 64x64 at (wr,wc)
  const int brow = blockIdx.x * 128, bcol = blockIdx.y * 128;
  const int r0 = lane & 15, kq = lane >> 4;

  f32x4 acc[4][4] = {};

  const int srow = tid >> 3, sc8 = (tid & 7) * 8;  // staging: 8 threads/row

  for (int k0 = 0; k0 < K; k0 += BK) {
    __syncthreads();
#pragma unroll
    for (int p = 0; p < 4; p++) {
      int row = p * 32 + srow;
      *reinterpret_cast<u16x8*>(&Asm[row][sc8]) =
          *reinterpret_cast<const u16x8*>(&A[(size_t)(brow + row) * K + k0 + sc8]);
      *reinterpret_cast<u16x8*>(&Bsm[row][sc8]) =
          *reinterpret_cast<const u16x8*>(&Bt[(size_t)(bcol + row) * K + k0 + sc8]);
    }
    __syncthreads();
#pragma unroll
    for (int c = 0; c < 2; c++) {  // two K=32 chunks
      bf16x8 af[4], bfr[4];
#pragma unroll
      for (int m = 0; m < 4; m++)
        af[m] = ld_frag(&Asm[wr * 64 + m * 16 + r0][c * 32 + kq * 8]);
#pragma unroll
      for (int n = 0; n < 4; n++)
        bfr[n] = ld_frag(&Bsm[wc * 64 + n * 16 + r0][c * 32 + kq * 8]);
#pragma unroll
      for (int m = 0; m < 4; m++)
#pragma unroll
        for (int n = 0; n < 4; n++)
          acc[m][n] = __builtin_amdgcn_mfma_f32_16x16x32_bf16(af[m], bfr[n], acc[m][n], 0, 0, 0);
    }
  }

  const int orow = kq * 4;
#pragma unroll
  for (int n = 0; n < 4; n++) {
#pragma unroll
    for (int m = 0; m < 4; m++) {
      int col = bcol + wc * 64 + n * 16 + r0;
      float bv = bias[col];
#pragma unroll
      for (int r = 0; r < 4; r++) {
        int row = brow + wr * 64 + m * 16 + orow + r;
        float v = acc[m][n][r] + bv;
        if (BF16_OUT)
          ((unsigned short*)Cv)[(size_t)row * N + col] = f2bf(v);
        else
          ((float*)Cv)[(size_t)row * N + col] = v;
      }
    }
  }
}

// ---- causal flash attention (swapped-QK^T, register-resident P) ----
// qkv bf16 [B*T][3C]; att bf16 [B*T][C]. Block: one (b,h) x 64 q-rows; 4 waves x 16 rows.
// St[k][q] fragments: lane holds q = lane&15 (full P row slice), k = 16s + 4*kq + r.
// V stored transposed with XOR swizzle: Vsm[d][tk ^ (d & 56)].
__global__ __launch_bounds__(256) void k_flash(const unsigned short* __restrict__ qkv,
                                               unsigned short* __restrict__ att, int T) {
  constexpr int C3 = 3072, C = 1024;
  __shared__ unsigned short Ksm[64][72];   // [tk][d]
  __shared__ unsigned short Vsm[64][72];   // [d][tk ^ (d&56)]

  const int tid = threadIdx.x, lane = tid & 63, w = tid >> 6;
  const int bh = blockIdx.x;  // b*16 + h
  const int qt = blockIdx.y;
  const int b = bh >> 4, h = bh & 15;
  const int q0 = qt * 64;
  const int r0 = lane & 15, kq = lane >> 4;

  const size_t rowbase = (size_t)b * T * C3;

  // Q fragments (b-operand: col=q=r0, k-slot=d)
  bf16x8 qf[2];
  {
    const unsigned short* qp = &qkv[rowbase + (size_t)(q0 + w * 16 + r0) * C3 + h * 64];
    qf[0] = ld_frag(&qp[kq * 8]);
    qf[1] = ld_frag(&qp[32 + kq * 8]);
  }

  f32x4 accO[4] = {};
  float m_run = NEG_INF, l_run = 0.f;

  const int q_my = q0 + w * 16 + r0;  // the softmax row this lane owns

  const int stk = tid >> 3, sd8 = (tid & 7) * 8;  // staging map (block-wide)

  for (int kt = 0; kt <= qt; kt++) {
    const int k0 = kt * 64;
    __syncthreads();
    // stage K row-major (b128) and V transposed+swizzled (conflict-free scalar scatter)
#pragma unroll
    for (int p = 0; p < 2; p++) {
      int tkk = p * 32 + stk;
      const size_t rb = rowbase + (size_t)(k0 + tkk) * C3 + h * 64 + sd8;
      *reinterpret_cast<u16x8*>(&Ksm[tkk][sd8]) =
          *reinterpret_cast<const u16x8*>(&qkv[rb + C]);
      u16x8 vv = *reinterpret_cast<const u16x8*>(&qkv[rb + 2 * C]);
      int tkx = tkk ^ sd8;  // (d&56) == sd8 for all 8 d in this vector
#pragma unroll
      for (int i = 0; i < 8; i++) Vsm[sd8 + i][tkx] = vv[i];
    }
    __syncthreads();

    // S^T = K @ Q^T : a-frag = K rows, b-frag = Q
    f32x4 st[4];
#pragma unroll
    for (int s = 0; s < 4; s++) {
      f32x4 a = {};
      a = __builtin_amdgcn_mfma_f32_16x16x32_bf16(ld_frag(&Ksm[s * 16 + r0][kq * 8]), qf[0], a, 0, 0, 0);
      a = __builtin_amdgcn_mfma_f32_16x16x32_bf16(ld_frag(&Ksm[s * 16 + r0][32 + kq * 8]), qf[1], a, 0, 0, 0);
      st[s] = a;
    }

    // scale + causal mask; lane's value (s,r) is S[q_my][k0 + 16s + 4kq + r]
    const bool diag = (kt == qt);
    float sv[4][4];
    float mx = NEG_INF;
#pragma unroll
    for (int s = 0; s < 4; s++) {
#pragma unroll
      for (int r = 0; r < 4; r++) {
        float x = st[s][r] * 0.125f;
        int kg = k0 + s * 16 + kq * 4 + r;
        if (diag && kg > q_my) x = NEG_INF;
        sv[s][r] = x;
        mx = fmaxf(mx, x);
      }
    }
    // row reduce across the 4 kq-groups holding this q
    mx = fmaxf(mx, __shfl_xor(mx, 16));
    mx = fmaxf(mx, __shfl_xor(mx, 32));
    float mn = fmaxf(m_run, mx);
    float corr = exp2f((m_run - mn) * LOG2E);
    m_run = mn;

    float ls = 0.f;
    unsigned short ph[4][4];
#pragma unroll
    for (int s = 0; s < 4; s++) {
#pragma unroll
      for (int r = 0; r < 4; r++) {
        float pv = exp2f((sv[s][r] - mn) * LOG2E);
        ls += pv;
        ph[s][r] = f2bf(pv);
      }
    }
    ls += __shfl_xor(ls, 16);
    ls += __shfl_xor(ls, 32);
    l_run = l_run * corr + ls;

    // rescale accO: lane's acc rows are q_local = 4*kq + r; corr lives at lane q_local
    float cq[4];
#pragma unroll
    for (int r = 0; r < 4; r++) cq[r] = __shfl(corr, kq * 4 + r);
#pragma unroll
    for (int n = 0; n < 4; n++)
#pragma unroll
      for (int r = 0; r < 4; r++) accO[n][r] *= cq[r];

    // PV: a-frag = lane-local P (slots j<4 from subtile 2t, j>=4 from 2t+1)
#pragma unroll
    for (int t = 0; t < 2; t++) {
      u16x8 pw;
#pragma unroll
      for (int r = 0; r < 4; r++) { pw[r] = ph[2 * t][r]; pw[4 + r] = ph[2 * t + 1][r]; }
      bf16x8 pa = __builtin_bit_cast(bf16x8, pw);
#pragma unroll
      for (int n = 0; n < 4; n++) {
        int d = n * 16 + r0;
        int swz = d & 56;
        const u16x4 lo = *reinterpret_cast<const u16x4*>(&Vsm[d][(t * 32 + kq * 4) ^ swz]);
        const u16x4 hi = *reinterpret_cast<const u16x4*>(&Vsm[d][(t * 32 + 16 + kq * 4) ^ swz]);
        u16x8 vb;
#pragma unroll
        for (int i = 0; i < 4; i++) { vb[i] = lo[i]; vb[4 + i] = hi[i]; }
        accO[n] = __builtin_amdgcn_mfma_f32_16x16x32_bf16(
            pa, __builtin_bit_cast(bf16x8, vb), accO[n], 0, 0, 0);
      }
    }
  }

  // epilogue: normalize, write att (bf16). acc rows: q_local = 4*kq + r, cols d = n*16 + r0
  float lq[4];
#pragma unroll
  for (int r = 0; r < 4; r++) lq[r] = __shfl(l_run, kq * 4 + r);
#pragma unroll
  for (int n = 0; n < 4; n++) {
#pragma unroll
    for (int r = 0; r < 4; r++) {
      int qrow = q0 + w * 16 + kq * 4 + r;
      float v = accO[n][r] / lq[r];
      att[((size_t)b * T + qrow) * C + h * 64 + n * 16 + r0] = f2bf(v);
    }
  }
}

extern "C" void kernel_launch(void* const* d_in, const int* in_sizes, int n_in,
                              void* d_out, int out_size, void* d_ws, size_t ws_size,
                              hipStream_t stream) {
  const float* x = (const float*)d_in[0];
  const float* w_qkv = (const float*)d_in[1];
  const float* b_qkv = (const float*)d_in[2];
  const float* w_proj = (const float*)d_in[3];
  const float* b_proj = (const float*)d_in[4];

  constexpr int B = 4, T = 2048, C = 1024, C3 = 3072;
  constexpr int M = B * T;  // 8192

  unsigned short* x_bf = (unsigned short*)d_ws;            // M*C
  unsigned short* wqkvT = x_bf + (size_t)M * C;            // C3*C
  unsigned short* wprojT = wqkvT + (size_t)C3 * C;         // C*C
  unsigned short* qkv = wprojT + (size_t)C * C;            // M*C3
  unsigned short* att = qkv + (size_t)M * C3;              // M*C

  hipLaunchKernelGGL(k_convert, dim3(2048), dim3(256), 0, stream, x, x_bf, M * C / 4);
  hipLaunchKernelGGL(k_transpose, dim3(C3 / 32, C / 32), dim3(256), 0, stream, w_qkv, wqkvT, C, C3);
  hipLaunchKernelGGL(k_transpose, dim3(C / 32, C / 32), dim3(256), 0, stream, w_proj, wprojT, C, C);
  hipLaunchKernelGGL((k_gemm<true>), dim3(M / 128, C3 / 128), dim3(256), 0, stream,
                     x_bf, wqkvT, b_qkv, (void*)qkv, M, C3, C);
  hipLaunchKernelGGL(k_flash, dim3(64, 32), dim3(256), 0, stream, qkv, att, T);
  hipLaunchKernelGGL((k_gemm<false>), dim3(M / 128, C / 128), dim3(256), 0, stream,
                     att, wprojT, b_proj, d_out, M, C, C);
}

// Round 4
// 191.442 us; speedup vs baseline: 1.5663x; 1.2146x over previous
//
#include <hip/hip_runtime.h>
#include <hip/hip_bf16.h>

// Causal self-attention: qkv = x@w_qkv + b_qkv; flash-attn (causal); out = att@w_proj + b_proj
// B=4, T=2048, C=1024, H=16, D=64. All matmuls bf16 MFMA 16x16x32, fp32 accumulate.
// R3: fixes r2 compile error (stray cast expression in P-pack). Content otherwise:
//     flash — cvt_pk P-pack, log2-domain scores, diag-tile split, defer-max (THR=8),
//     double-buffered LDS with early global loads (T14), setprio around MFMA (T5),
//     reversed qt dispatch (long blocks first).
//     gemm — m97 structure: linear LDS + global_load_lds width=16.

typedef __bf16 bf16x8 __attribute__((ext_vector_type(8)));
typedef float f32x4 __attribute__((ext_vector_type(4)));
typedef unsigned short u16x8 __attribute__((ext_vector_type(8)));
typedef unsigned short u16x4 __attribute__((ext_vector_type(4)));
typedef unsigned int u32;

#define LOG2E 1.44269504088896340736f
#define NEG_INF (-__builtin_inff())

#define AS_GLOBAL(p) ((const __attribute__((address_space(1))) u32*)(p))
#define AS_LDS(p) ((__attribute__((address_space(3))) u32*)(p))

__device__ __forceinline__ unsigned short f2bf(float f) {
  unsigned int u = __builtin_bit_cast(unsigned int, f);
  u += 0x7fff + ((u >> 16) & 1);   // RNE
  return (unsigned short)(u >> 16);
}

__device__ __forceinline__ u32 cvt_pk_bf16(float lo, float hi) {
  u32 r;
  asm("v_cvt_pk_bf16_f32 %0, %1, %2" : "=v"(r) : "v"(lo), "v"(hi));
  return r;
}

__device__ __forceinline__ bf16x8 ld_frag(const unsigned short* p) {
  return __builtin_bit_cast(bf16x8, *reinterpret_cast<const u16x8*>(p));
}

// ---- fp32 -> bf16 elementwise (x) ----
__global__ void k_convert(const float* __restrict__ in, unsigned short* __restrict__ out, int n4) {
  int i = blockIdx.x * blockDim.x + threadIdx.x;
  int stride = gridDim.x * blockDim.x;
  for (; i < n4; i += stride) {
    float4 v = reinterpret_cast<const float4*>(in)[i];
    u16x4 o = { f2bf(v.x), f2bf(v.y), f2bf(v.z), f2bf(v.w) };
    reinterpret_cast<u16x4*>(out)[i] = o;
  }
}

// ---- fp32 [K][N] -> bf16 [N][K] transpose (weights) ----
__global__ void k_transpose(const float* __restrict__ in, unsigned short* __restrict__ out,
                            int K, int N) {
  __shared__ float tile[32][33];
  int n0 = blockIdx.x * 32, k0 = blockIdx.y * 32;
  int tx = threadIdx.x & 31, ty = threadIdx.x >> 5;  // 32 x 8
#pragma unroll
  for (int i = 0; i < 4; i++)
    tile[ty + i * 8][tx] = in[(size_t)(k0 + ty + i * 8) * N + n0 + tx];
  __syncthreads();
#pragma unroll
  for (int i = 0; i < 4; i++)
    out[(size_t)(n0 + ty + i * 8) * K + k0 + tx] = f2bf(tile[tx][ty + i * 8]);
}

// ---- bf16 GEMM (m97 structure): C[M][N] = A[M][K] @ Bt[N][K]^T + bias ----
template <bool BF16_OUT>
__global__ __launch_bounds__(256) void k_gemm(
    const unsigned short* __restrict__ A, const unsigned short* __restrict__ Bt,
    const float* __restrict__ bias, void* __restrict__ Cv, int M, int N, int K) {
  constexpr int BK = 64;
  __shared__ unsigned short Asm[128][BK];  // linear — global_load_lds writes lane-contiguous
  __shared__ unsigned short Bsm[128][BK];
  const int tid = threadIdx.x;
  const int lane = tid & 63, w = tid >> 6;
  const int wr = w >> 1, wc = w & 1;
  const int brow = blockIdx.x * 128, bcol = blockIdx.y * 128;
  const int r0 = lane & 15, kq = lane >> 4;

  f32x4 acc[4][4] = {};

  // staging: chunk c (= w*4+q) covers rows c*8..c*8+7; lane i -> row c*8+(i>>3), col (i&7)*8
  const int srow = lane >> 3, scol = (lane & 7) * 8;

  for (int k0 = 0; k0 < K; k0 += BK) {
    __syncthreads();  // previous tile's reads done
#pragma unroll
    for (int q = 0; q < 4; q++) {
      int c = w * 4 + q;
      const unsigned short* ga = &A[(size_t)(brow + c * 8 + srow) * K + k0 + scol];
      const unsigned short* gb = &Bt[(size_t)(bcol + c * 8 + srow) * K + k0 + scol];
      __builtin_amdgcn_global_load_lds(AS_GLOBAL(ga), AS_LDS(&Asm[c * 8][0]), 16, 0, 0);
      __builtin_amdgcn_global_load_lds(AS_GLOBAL(gb), AS_LDS(&Bsm[c * 8][0]), 16, 0, 0);
    }
    __syncthreads();  // drains vmcnt -> LDS ready
#pragma unroll
    for (int c = 0; c < 2; c++) {
      bf16x8 af[4], bfr[4];
#pragma unroll
      for (int m = 0; m < 4; m++)
        af[m] = ld_frag(&Asm[wr * 64 + m * 16 + r0][c * 32 + kq * 8]);
#pragma unroll
      for (int n = 0; n < 4; n++)
        bfr[n] = ld_frag(&Bsm[wc * 64 + n * 16 + r0][c * 32 + kq * 8]);
      __builtin_amdgcn_s_setprio(1);
#pragma unroll
      for (int m = 0; m < 4; m++)
#pragma unroll
        for (int n = 0; n < 4; n++)
          acc[m][n] = __builtin_amdgcn_mfma_f32_16x16x32_bf16(af[m], bfr[n], acc[m][n], 0, 0, 0);
      __builtin_amdgcn_s_setprio(0);
    }
  }

  const int orow = kq * 4;
#pragma unroll
  for (int n = 0; n < 4; n++) {
#pragma unroll
    for (int m = 0; m < 4; m++) {
      int col = bcol + wc * 64 + n * 16 + r0;
      float bv = bias[col];
#pragma unroll
      for (int r = 0; r < 4; r++) {
        int row = brow + wr * 64 + m * 16 + orow + r;
        float v = acc[m][n][r] + bv;
        if (BF16_OUT)
          ((unsigned short*)Cv)[(size_t)row * N + col] = f2bf(v);
        else
          ((float*)Cv)[(size_t)row * N + col] = v;
      }
    }
  }
}

// ---- causal flash attention (swapped-QK^T, register P, dbuf LDS, defer-max) ----
__global__ __launch_bounds__(256) void k_flash(const unsigned short* __restrict__ qkv,
                                               unsigned short* __restrict__ att, int T) {
  constexpr int C3 = 3072, C = 1024;
  __shared__ unsigned short Ksm[2][64][72];   // [buf][tk][d]
  __shared__ unsigned short Vsm[2][64][72];   // [buf][d][tk ^ (d&56)]

  const int tid = threadIdx.x, lane = tid & 63, w = tid >> 6;
  const int bh = blockIdx.x;
  const int qt = gridDim.y - 1 - blockIdx.y;  // long blocks dispatched first
  const int b = bh >> 4, h = bh & 15;
  const int q0 = qt * 64;
  const int r0 = lane & 15, kq = lane >> 4;

  const size_t rowbase = (size_t)b * T * C3;

  bf16x8 qf[2];
  {
    const unsigned short* qp = &qkv[rowbase + (size_t)(q0 + w * 16 + r0) * C3 + h * 64];
    qf[0] = ld_frag(&qp[kq * 8]);
    qf[1] = ld_frag(&qp[32 + kq * 8]);
  }

  f32x4 accO[4] = {};
  float m_run = NEG_INF, l_run = 0.f;
  const int q_my = q0 + w * 16 + r0;  // softmax row this lane owns

  const int stk = tid >> 3, sd8 = (tid & 7) * 8;

  u16x8 kreg[2], vreg[2];
  auto LOADT = [&](int kt) {
#pragma unroll
    for (int p = 0; p < 2; p++) {
      const size_t rb = rowbase + (size_t)(kt * 64 + p * 32 + stk) * C3 + h * 64 + sd8;
      kreg[p] = *reinterpret_cast<const u16x8*>(&qkv[rb + C]);
      vreg[p] = *reinterpret_cast<const u16x8*>(&qkv[rb + 2 * C]);
    }
  };
  auto WRITET = [&](int buf) {
#pragma unroll
    for (int p = 0; p < 2; p++) {
      int tkk = p * 32 + stk;
      *reinterpret_cast<u16x8*>(&Ksm[buf][tkk][sd8]) = kreg[p];
      int tkx = tkk ^ sd8;  // (d&56)==sd8 for all 8 d in this vector
#pragma unroll
      for (int i = 0; i < 8; i++) Vsm[buf][sd8 + i][tkx] = vreg[p][i];
    }
  };

  constexpr float SCL = 0.125f * LOG2E;  // log2-domain score scale
  auto TILE = [&](int buf, int k0, bool diag) {
    // S^T = K @ Q^T
    f32x4 st[4];
    __builtin_amdgcn_s_setprio(1);
#pragma unroll
    for (int s = 0; s < 4; s++) {
      f32x4 a = {};
      a = __builtin_amdgcn_mfma_f32_16x16x32_bf16(
          ld_frag(&Ksm[buf][s * 16 + r0][kq * 8]), qf[0], a, 0, 0, 0);
      a = __builtin_amdgcn_mfma_f32_16x16x32_bf16(
          ld_frag(&Ksm[buf][s * 16 + r0][32 + kq * 8]), qf[1], a, 0, 0, 0);
      st[s] = a;
    }
    __builtin_amdgcn_s_setprio(0);

    float sv[4][4];
    float mx = NEG_INF;
#pragma unroll
    for (int s = 0; s < 4; s++) {
#pragma unroll
      for (int r = 0; r < 4; r++) {
        float x = st[s][r] * SCL;
        if (diag) {
          int kg = k0 + s * 16 + kq * 4 + r;
          if (kg > q_my) x = NEG_INF;
        }
        sv[s][r] = x;
      }
      // encourage v_max3
      mx = fmaxf(fmaxf(mx, sv[s][0]), sv[s][1]);
      mx = fmaxf(fmaxf(mx, sv[s][2]), sv[s][3]);
    }
    mx = fmaxf(mx, __shfl_xor(mx, 16));
    mx = fmaxf(mx, __shfl_xor(mx, 32));

    // defer-max: rescale only when the row max grew by > 8 (log2 units)
    if (__any(mx > m_run + 8.f)) {
      float mn = fmaxf(m_run, mx);
      float corr = exp2f(m_run - mn);
      m_run = mn;
      l_run *= corr;
      float cq[4];
#pragma unroll
      for (int r = 0; r < 4; r++) cq[r] = __shfl(corr, kq * 4 + r);
#pragma unroll
      for (int n = 0; n < 4; n++)
#pragma unroll
        for (int r = 0; r < 4; r++) accO[n][r] *= cq[r];
    }

    float pv[4][4];
    float ls = 0.f;
#pragma unroll
    for (int s = 0; s < 4; s++)
#pragma unroll
      for (int r = 0; r < 4; r++) {
        float p = exp2f(sv[s][r] - m_run);
        pv[s][r] = p;
        ls += p;
      }
    ls += __shfl_xor(ls, 16);
    ls += __shfl_xor(ls, 32);
    l_run += ls;

    // PV: pack P via cvt_pk; B-frag = V^T quads from swizzled LDS
    __builtin_amdgcn_s_setprio(1);
#pragma unroll
    for (int t = 0; t < 2; t++) {
      u32 pd[4];
      pd[0] = cvt_pk_bf16(pv[2 * t][0], pv[2 * t][1]);
      pd[1] = cvt_pk_bf16(pv[2 * t][2], pv[2 * t][3]);
      pd[2] = cvt_pk_bf16(pv[2 * t + 1][0], pv[2 * t + 1][1]);
      pd[3] = cvt_pk_bf16(pv[2 * t + 1][2], pv[2 * t + 1][3]);
      bf16x8 pa = __builtin_bit_cast(bf16x8, *reinterpret_cast<u16x8*>(pd));
#pragma unroll
      for (int n = 0; n < 4; n++) {
        int d = n * 16 + r0;
        int swz = d & 56;
        const u16x4 lo = *reinterpret_cast<const u16x4*>(&Vsm[buf][d][(t * 32 + kq * 4) ^ swz]);
        const u16x4 hi = *reinterpret_cast<const u16x4*>(&Vsm[buf][d][(t * 32 + 16 + kq * 4) ^ swz]);
        u16x8 vb;
#pragma unroll
        for (int i = 0; i < 4; i++) { vb[i] = lo[i]; vb[4 + i] = hi[i]; }
        accO[n] = __builtin_amdgcn_mfma_f32_16x16x32_bf16(
            pa, __builtin_bit_cast(bf16x8, vb), accO[n], 0, 0, 0);
      }
    }
    __builtin_amdgcn_s_setprio(0);
  };

  int buf = 0;
  LOADT(0);
  WRITET(0);
  for (int kt = 0; kt < qt; kt++) {
    __syncthreads();           // buf data visible; other buf's reads done
    LOADT(kt + 1);             // issue next tile's global loads early
    TILE(buf, kt * 64, false); // compute current (hides HBM latency)
    WRITET(buf ^ 1);           // vmcnt wait lands here
    buf ^= 1;
  }
  __syncthreads();
  TILE(buf, qt * 64, true);    // diagonal tile (masked)

  // epilogue: normalize, write att
  float lq[4];
#pragma unroll
  for (int r = 0; r < 4; r++) lq[r] = __shfl(l_run, kq * 4 + r);
#pragma unroll
  for (int n = 0; n < 4; n++) {
#pragma unroll
    for (int r = 0; r < 4; r++) {
      int qrow = q0 + w * 16 + kq * 4 + r;
      float v = accO[n][r] / lq[r];
      att[((size_t)b * T + qrow) * C + h * 64 + n * 16 + r0] = f2bf(v);
    }
  }
}

extern "C" void kernel_launch(void* const* d_in, const int* in_sizes, int n_in,
                              void* d_out, int out_size, void* d_ws, size_t ws_size,
                              hipStream_t stream) {
  const float* x = (const float*)d_in[0];
  const float* w_qkv = (const float*)d_in[1];
  const float* b_qkv = (const float*)d_in[2];
  const float* w_proj = (const float*)d_in[3];
  const float* b_proj = (const float*)d_in[4];

  constexpr int B = 4, T = 2048, C = 1024, C3 = 3072;
  constexpr int M = B * T;  // 8192

  unsigned short* x_bf = (unsigned short*)d_ws;            // M*C
  unsigned short* wqkvT = x_bf + (size_t)M * C;            // C3*C
  unsigned short* wprojT = wqkvT + (size_t)C3 * C;         // C*C
  unsigned short* qkv = wprojT + (size_t)C * C;            // M*C3
  unsigned short* att = qkv + (size_t)M * C3;              // M*C

  hipLaunchKernelGGL(k_convert, dim3(2048), dim3(256), 0, stream, x, x_bf, M * C / 4);
  hipLaunchKernelGGL(k_transpose, dim3(C3 / 32, C / 32), dim3(256), 0, stream, w_qkv, wqkvT, C, C3);
  hipLaunchKernelGGL(k_transpose, dim3(C / 32, C / 32), dim3(256), 0, stream, w_proj, wprojT, C, C);
  hipLaunchKernelGGL((k_gemm<true>), dim3(M / 128, C3 / 128), dim3(256), 0, stream,
                     x_bf, wqkvT, b_qkv, (void*)qkv, M, C3, C);
  hipLaunchKernelGGL(k_flash, dim3(64, 32), dim3(256), 0, stream, qkv, att, T);
  hipLaunchKernelGGL((k_gemm<false>), dim3(M / 128, C / 128), dim3(256), 0, stream,
                     att, wprojT, b_proj, d_out, M, C, C);
}